// Round 4
// baseline (1017.474 us; speedup 1.0000x reference)
//
#include <hip/hip_runtime.h>
#include <hip/hip_bf16.h>

#define B_  4
#define T_  2048
#define D_  1024
#define H_  16
#define HD_ 64
#define M_  (B_*T_)   // 8192
#define CH_ 16        // scan chunk (steps per LDS buffer)

typedef __attribute__((ext_vector_type(4))) float f32x4;
typedef __attribute__((ext_vector_type(8))) short bf16x8;

__device__ __forceinline__ float sigmoidf_(float x){ return 1.0f/(1.0f+__expf(-x)); }
__device__ __forceinline__ float siluf_(float x){ return x/(1.0f+__expf(-x)); }

// f32 -> bf16 (RNE), raw ushort
__device__ __forceinline__ unsigned short f2bf(float f){
  unsigned int u = __float_as_uint(f);
  unsigned int r = (u + 0x7FFFu + ((u >> 16) & 1u)) >> 16;
  return (unsigned short)r;
}
__device__ __forceinline__ float bf2f(unsigned short u){
  return __uint_as_float(((unsigned int)u) << 16);
}

// async global->LDS, 16 bytes per lane (dest = wave-uniform base + lane*16)
__device__ __forceinline__ void gload16(const void* g, void* l){
  using GP = const __attribute__((address_space(1))) unsigned int*;
  using LP = __attribute__((address_space(3))) unsigned int*;
  __builtin_amdgcn_global_load_lds(
      reinterpret_cast<GP>(reinterpret_cast<unsigned long long>(g)),
      reinterpret_cast<LP>(reinterpret_cast<unsigned long long>(l)),
      16, 0, 0);
}

// ---------------- converts ----------------
__global__ __launch_bounds__(256) void k_f32_to_bf16(const float* __restrict__ src,
                                                     unsigned short* __restrict__ dst, int n){
  int i = (blockIdx.x * 256 + threadIdx.x) * 4;
  if (i >= n) return;
  float4 v = *reinterpret_cast<const float4*>(src + i);
  ushort4 o;
  o.x = f2bf(v.x); o.y = f2bf(v.y); o.z = f2bf(v.z); o.w = f2bf(v.w);
  *reinterpret_cast<ushort4*>(dst + i) = o;
}

// dst[Nd][K] bf16 = transpose(src[K][Ns]); rows Ns..Nd zero-padded
__global__ void k_transpose_bf16(const float* __restrict__ src, unsigned short* __restrict__ dst,
                                 int K, int Ns, int Nd){
  __shared__ float tile[32][33];
  int k0 = blockIdx.x * 32, n0 = blockIdx.y * 32;
  int lx = threadIdx.x, ly = threadIdx.y;           // 32 x 8
  for (int i = ly; i < 32; i += 8){
    int n = n0 + lx;
    tile[i][lx] = (n < Ns) ? src[(size_t)(k0 + i) * Ns + n] : 0.0f;
  }
  __syncthreads();
  for (int i = ly; i < 32; i += 8){
    int n = n0 + i;
    if (n < Nd) dst[(size_t)n * K + k0 + lx] = f2bf(tile[lx][i]);
  }
}

// ---------------- bf16 MFMA GEMM: C[M,N] = A[M,K(lda)] * BT[N,K]^T ----------------
// 128x128 tile, BK=32, 4 waves (2x2), 16x16x32 MFMA, global_load_lds + XOR swizzle.
// EPI: 0 = f32 store, 1 = bf16, 2 = silu->bf16, 3 = sigmoid->bf16,
//      4 = silu + per-64col-head l2norm -> bf16, 5 = bf16 + gamma side-channel (cols<16)
template<int EPI>
__global__ __launch_bounds__(256) void k_gemm(const unsigned short* __restrict__ A,
                                              const unsigned short* __restrict__ BT,
                                              void* __restrict__ Cout,
                                              int K, int lda, int ldc,
                                              float* __restrict__ extra){
  __shared__ __align__(16) unsigned short As[128*32];
  __shared__ __align__(16) unsigned short Bs[128*32];
  const int tid = threadIdx.x;
  const int l = tid & 63, w = tid >> 6;
  const int wm = w >> 1, wn = w & 1;
  const int m0 = blockIdx.y * 128, n0 = blockIdx.x * 128;
  const int lr = l & 15, kg = l >> 4;

  f32x4 acc[4][4];
#pragma unroll
  for (int i = 0; i < 4; ++i)
#pragma unroll
    for (int j = 0; j < 4; ++j) acc[i][j] = 0.0f;

  for (int kt = 0; kt < K; kt += 32){
    __syncthreads();
    {
      int ch = tid;
      int row = ch >> 2;
      int sw  = (row & 3) ^ ((row >> 2) & 3);
      int cc  = (ch & 3) ^ sw;
      gload16(A  + (size_t)(m0 + row) * lda + kt + cc * 8, (char*)As + ch * 16);
      gload16(BT + (size_t)(n0 + row) * K   + kt + cc * 8, (char*)Bs + ch * 16);
      ch = tid + 256;
      row = ch >> 2;
      sw  = (row & 3) ^ ((row >> 2) & 3);
      cc  = (ch & 3) ^ sw;
      gload16(A  + (size_t)(m0 + row) * lda + kt + cc * 8, (char*)As + ch * 16);
      gload16(BT + (size_t)(n0 + row) * K   + kt + cc * 8, (char*)Bs + ch * 16);
    }
    __syncthreads();

    bf16x8 af[4], bfr[4];
#pragma unroll
    for (int mi = 0; mi < 4; ++mi){
      int row = wm*64 + mi*16 + lr;
      int sw  = (row & 3) ^ ((row >> 2) & 3);
      af[mi]  = *reinterpret_cast<const bf16x8*>((const char*)As + row*64 + ((kg ^ sw) * 16));
    }
#pragma unroll
    for (int ni = 0; ni < 4; ++ni){
      int col = wn*64 + ni*16 + lr;
      int sw  = (col & 3) ^ ((col >> 2) & 3);
      bfr[ni] = *reinterpret_cast<const bf16x8*>((const char*)Bs + col*64 + ((kg ^ sw) * 16));
    }
#pragma unroll
    for (int mi = 0; mi < 4; ++mi)
#pragma unroll
      for (int ni = 0; ni < 4; ++ni)
        acc[mi][ni] = __builtin_amdgcn_mfma_f32_16x16x32_bf16(af[mi], bfr[ni], acc[mi][ni], 0, 0, 0);
  }

#pragma unroll
  for (int mi = 0; mi < 4; ++mi){
    if (EPI == 4){
      // silu then l2-normalize each row over this wave's 64-col head block
#pragma unroll
      for (int r = 0; r < 4; ++r){
        float vals[4]; float ss = 0.0f;
#pragma unroll
        for (int ni = 0; ni < 4; ++ni){ vals[ni] = siluf_(acc[mi][ni][r]); ss += vals[ni]*vals[ni]; }
        ss += __shfl_xor(ss, 1); ss += __shfl_xor(ss, 2);
        ss += __shfl_xor(ss, 4); ss += __shfl_xor(ss, 8);
        const float inv = 1.0f / fmaxf(sqrtf(ss), 1e-12f);
        const int row = m0 + wm*64 + mi*16 + kg*4 + r;
#pragma unroll
        for (int ni = 0; ni < 4; ++ni){
          const int col = n0 + wn*64 + ni*16 + lr;
          ((unsigned short*)Cout)[(size_t)row*ldc + col] = f2bf(vals[ni]*inv);
        }
      }
    } else {
#pragma unroll
      for (int ni = 0; ni < 4; ++ni)
#pragma unroll
        for (int r = 0; r < 4; ++r){
          const int row = m0 + wm*64 + mi*16 + kg*4 + r;
          const int col = n0 + wn*64 + ni*16 + lr;
          const float v = acc[mi][ni][r];
          if (EPI == 0){
            ((float*)Cout)[(size_t)row*ldc + col] = v;
          } else {
            float ov = v;
            if (EPI == 2) ov = siluf_(v);
            if (EPI == 3) ov = sigmoidf_(v);
            ((unsigned short*)Cout)[(size_t)row*ldc + col] = f2bf(ov);
            if (EPI == 5 && col < 16)
              extra[((size_t)(row >> 11) * 16 + col) * 2048 + (row & 2047)] = -sigmoidf_(v);
          }
        }
    }
  }
}

// ---------------- sequential DPLR scan ----------------
// grid: 512 blocks; bh = blk&63, vg = blk>>6 (vg-siblings share L2 locality).
// 64 threads (one wave, no barriers). lane: c = l&7 (output column), kseg = l>>3.
// S[k][col]: 2x f32x4 per lane. Reads q/k/ef/v straight from [tok][1024] bf16
// projection buffers (activations pre-applied in GEMM epilogues). Double-buffered
// bf16 LDS staging via global_load_lds; per-chunk batch bf16->f32 convert.
__global__ __launch_bounds__(64) void k_scan(const unsigned short* __restrict__ qb,
                                             const unsigned short* __restrict__ kb,
                                             const unsigned short* __restrict__ vb,
                                             const unsigned short* __restrict__ eb,
                                             const float* __restrict__ gammac,
                                             unsigned short* __restrict__ o){
  __shared__ __align__(16) unsigned short qS[2][CH_*64];
  __shared__ __align__(16) unsigned short kS[2][CH_*64];
  __shared__ __align__(16) unsigned short eS[2][CH_*64];
  __shared__ __align__(16) unsigned short vS[2][CH_*8];
  __shared__ __align__(16) float qF[CH_*64];
  __shared__ __align__(16) float kF[CH_*64];
  __shared__ __align__(16) float eF[CH_*64];

  const int bh = blockIdx.x & 63, vg = blockIdx.x >> 6;
  const int l = threadIdx.x;
  const int c = l & 7, kseg = l >> 3;
  const int b = bh >> 4, h = bh & 15;
  const int bT = b * T_;
  const int hc = h * HD_;
  const float* gb = gammac + (size_t)bh * T_;

  f32x4 S0 = 0.0f, S1 = 0.0f;

  auto stage = [&](int nb, int chk){
    const int t0 = chk * CH_;
#pragma unroll
    for (int i = 0; i < 2; ++i){
      const size_t src = (size_t)(bT + t0 + i*8 + (l>>3)) * D_ + hc + (l&7)*8;
      gload16(qb + src, (char*)&qS[nb][0] + i*1024 + l*16);
      gload16(kb + src, (char*)&kS[nb][0] + i*1024 + l*16);
      gload16(eb + src, (char*)&eS[nb][0] + i*1024 + l*16);
    }
    if (l < CH_)
      gload16(vb + (size_t)(bT + t0 + l) * D_ + hc + vg*8,
              (char*)&vS[nb][0] + l*16);
  };

  stage(0, 0);
  float gv = (l < CH_) ? gb[l] : 0.0f;
  asm volatile("s_waitcnt vmcnt(0)" ::: "memory");
  __builtin_amdgcn_sched_barrier(0);

  unsigned short* ob = o + (size_t)bT * D_ + hc + vg*8 + c;

  for (int chk = 0; chk < T_/CH_; ++chk){
    const int cur = chk & 1;
    float gvn = 0.0f;
    if (chk + 1 < T_/CH_){
      stage(cur ^ 1, chk + 1);
      if (l < CH_) gvn = gb[(chk+1)*CH_ + l];
    }
    // batch bf16->f32 convert of q,k,ef (each elem converted once per chunk)
#pragma unroll
    for (int p = 0; p < 2; ++p){
      bf16x8 a  = *(const bf16x8*)((const char*)&qS[cur][0] + p*1024 + l*16);
      bf16x8 bq = *(const bf16x8*)((const char*)&kS[cur][0] + p*1024 + l*16);
      bf16x8 ee = *(const bf16x8*)((const char*)&eS[cur][0] + p*1024 + l*16);
#pragma unroll
      for (int j = 0; j < 8; ++j){
        qF[p*512 + l*8 + j] = bf2f((unsigned short)a[j]);
        kF[p*512 + l*8 + j] = bf2f((unsigned short)bq[j]);
        eF[p*512 + l*8 + j] = bf2f((unsigned short)ee[j]);
      }
    }
    asm volatile("s_waitcnt lgkmcnt(0)" ::: "memory");
    __builtin_amdgcn_sched_barrier(0);

#pragma unroll 4
    for (int s = 0; s < CH_; ++s){
      const int eoff = s*64 + kseg*8;
      f32x4 E0 = *(const f32x4*)&eF[eoff];
      f32x4 E1 = *(const f32x4*)&eF[eoff+4];
      f32x4 K0 = *(const f32x4*)&kF[eoff];
      f32x4 K1 = *(const f32x4*)&kF[eoff+4];
      f32x4 Q0 = *(const f32x4*)&qF[eoff];
      f32x4 Q1 = *(const f32x4*)&qF[eoff+4];
      float vv = bf2f(vS[cur][s*8 + c]);
      float gs = __shfl(gv, s);
      S0 *= E0; S1 *= E1;                        // decay
      f32x4 ke0 = K0*E0, ke1 = K1*E1;
      f32x4 sv = ke0*S0 + ke1*S1;                // (k*ef)^T S'
      float red = (sv[0]+sv[1]) + (sv[2]+sv[3]);
      red += __shfl_xor(red, 8);
      red += __shfl_xor(red, 16);
      red += __shfl_xor(red, 32);
      float tv = fmaf(gs, red, vv);              // gamma*sab + v
      S0 += K0*tv; S1 += K1*tv;                  // S += k (sab+v)
      f32x4 ovv = Q0*S0 + Q1*S1;
      float out = (ovv[0]+ovv[1]) + (ovv[2]+ovv[3]);
      out += __shfl_xor(out, 8);
      out += __shfl_xor(out, 16);
      out += __shfl_xor(out, 32);
      if (kseg == 0) ob[(size_t)(chk*CH_ + s) * D_] = f2bf(out);
    }
    asm volatile("s_waitcnt vmcnt(0)" ::: "memory");
    __builtin_amdgcn_sched_barrier(0);
    gv = gvn;
  }
}

// ---------------- output gate (pre-sigmoided) + layernorm -> bf16 ----------------
__global__ __launch_bounds__(256) void k_gate_ln(const unsigned short* __restrict__ o,
                                                 const unsigned short* __restrict__ ogs,
                                                 const float* __restrict__ nw,
                                                 unsigned short* __restrict__ onb){
  const int tok = blockIdx.x;
  const int tid = threadIdx.x;
  const size_t base = (size_t)tok * D_ + tid * 4;
  ushort4 o4 = *(const ushort4*)(o + base);
  ushort4 g4 = *(const ushort4*)(ogs + base);
  float ov[4] = { bf2f(o4.x), bf2f(o4.y), bf2f(o4.z), bf2f(o4.w) };
  ov[0] *= bf2f(g4.x); ov[1] *= bf2f(g4.y);
  ov[2] *= bf2f(g4.z); ov[3] *= bf2f(g4.w);
  float s1 = ov[0] + ov[1] + ov[2] + ov[3];
  float s2 = ov[0]*ov[0] + ov[1]*ov[1] + ov[2]*ov[2] + ov[3]*ov[3];
#pragma unroll
  for (int off = 1; off < 64; off <<= 1){ s1 += __shfl_xor(s1, off); s2 += __shfl_xor(s2, off); }
  __shared__ float w1[4], w2[4];
  const int w = tid >> 6;
  if ((tid & 63) == 0){ w1[w] = s1; w2[w] = s2; }
  __syncthreads();
  s1 = w1[0] + w1[1] + w1[2] + w1[3];
  s2 = w2[0] + w2[1] + w2[2] + w2[3];
  const float mu  = s1 * (1.0f/1024.0f);
  const float var = s2 * (1.0f/1024.0f) - mu*mu;
  const float rs  = rsqrtf(var + 1e-5f);
  const float4 n4 = *(const float4*)(nw + tid * 4);
  ushort4 ou;
  ou.x = f2bf((ov[0] - mu) * rs * n4.x);
  ou.y = f2bf((ov[1] - mu) * rs * n4.y);
  ou.z = f2bf((ov[2] - mu) * rs * n4.z);
  ou.w = f2bf((ov[3] - mu) * rs * n4.w);
  *(ushort4*)(onb + base) = ou;
}

// ---------------- launcher ----------------
extern "C" void kernel_launch(void* const* d_in, const int* in_sizes, int n_in,
                              void* d_out, int out_size, void* d_ws, size_t ws_size,
                              hipStream_t stream){
  const float* x    = (const float*)d_in[0];
  const float* Wq   = (const float*)d_in[1];
  const float* Wk   = (const float*)d_in[2];
  const float* Wv   = (const float*)d_in[3];
  const float* Wg   = (const float*)d_in[4];
  const float* Wf1  = (const float*)d_in[5];
  const float* Wf2  = (const float*)d_in[6];
  const float* Wog1 = (const float*)d_in[7];
  const float* Wog2 = (const float*)d_in[8];
  const float* nw   = (const float*)d_in[9];
  const float* Wo   = (const float*)d_in[10];

  // workspace budget: 97,779,712 bytes. If the harness gives less, bail out
  // cleanly (output stays poisoned -> clean fail instead of a memory-fault abort).
  if (ws_size < 97779712ull) return;

  char* base = (char*)d_ws;
  size_t off = 0;
  auto alloc = [&](size_t bytes)->char*{
    char* r = base + off; off += (bytes + 255) & ~(size_t)255; return r;
  };
  unsigned short* xb    = (unsigned short*)alloc((size_t)M_*D_*2);      // 16MB (scan out reuses)
  unsigned short* WqT   = (unsigned short*)alloc((size_t)D_*D_*2);      // 2MB
  unsigned short* WkT   = (unsigned short*)alloc((size_t)D_*D_*2);
  unsigned short* WvT   = (unsigned short*)alloc((size_t)D_*D_*2);
  unsigned short* WoT   = (unsigned short*)alloc((size_t)D_*D_*2);
  unsigned short* WgfoT = (unsigned short*)alloc((size_t)256*D_*2);     // 0.5MB
  unsigned short* Wf2T  = (unsigned short*)alloc((size_t)D_*64*2);      // 128KB
  unsigned short* Wog2T = (unsigned short*)alloc((size_t)D_*64*2);
  unsigned short* qb    = (unsigned short*)alloc((size_t)M_*D_*2);      // 16MB (og-sig reuses)
  unsigned short* kb    = (unsigned short*)alloc((size_t)M_*D_*2);      // 16MB (LN out reuses)
  unsigned short* vb    = (unsigned short*)alloc((size_t)M_*D_*2);      // 16MB
  unsigned short* gfo   = (unsigned short*)alloc((size_t)M_*256*2);     // 4MB
  unsigned short* efb   = (unsigned short*)alloc((size_t)M_*D_*2);      // 16MB
  float*          gammac= (float*)alloc((size_t)64*T_*4);               // 0.5MB
  // aliases (strictly ordered reuse):
  unsigned short* obuf = xb;   // xb dead after level-1 GEMMs; scan writes here
  unsigned short* ogs  = qb;   // qb dead after scan; og-sigmoid GEMM writes here
  unsigned short* onb  = kb;   // kb dead after scan; gate_ln writes here

  dim3 blkT(32, 8);

  // converts / transposes
  k_f32_to_bf16<<<8192, 256, 0, stream>>>(x, xb, M_*D_);
  k_transpose_bf16<<<dim3(32,32), blkT, 0, stream>>>(Wq,   WqT,  1024, 1024, 1024);
  k_transpose_bf16<<<dim3(32,32), blkT, 0, stream>>>(Wk,   WkT,  1024, 1024, 1024);
  k_transpose_bf16<<<dim3(32,32), blkT, 0, stream>>>(Wv,   WvT,  1024, 1024, 1024);
  k_transpose_bf16<<<dim3(32,32), blkT, 0, stream>>>(Wo,   WoT,  1024, 1024, 1024);
  // fused bottleneck weights: rows 0-15 Wg^T, 16-79 Wf1^T, 80-143 Wog1^T, 144-255 zero
  k_transpose_bf16<<<dim3(32,1),  blkT, 0, stream>>>(Wg,   WgfoT,            1024, 16,  16);
  k_transpose_bf16<<<dim3(32,2),  blkT, 0, stream>>>(Wf1,  WgfoT + 16*1024,  1024, 64,  64);
  k_transpose_bf16<<<dim3(32,6),  blkT, 0, stream>>>(Wog1, WgfoT + 80*1024,  1024, 64, 176);
  k_transpose_bf16<<<dim3(2,32),  blkT, 0, stream>>>(Wf2,  Wf2T,  64, 1024, 1024);
  k_transpose_bf16<<<dim3(2,32),  blkT, 0, stream>>>(Wog2, Wog2T, 64, 1024, 1024);

  // level-1 projections with fused activations
  k_gemm<2><<<dim3(8,64), 256, 0, stream>>>(xb, WqT,   qb,  1024, 1024, 1024, nullptr); // silu
  k_gemm<4><<<dim3(8,64), 256, 0, stream>>>(xb, WkT,   kb,  1024, 1024, 1024, nullptr); // silu+l2norm
  k_gemm<1><<<dim3(8,64), 256, 0, stream>>>(xb, WvT,   vb,  1024, 1024, 1024, nullptr); // plain
  k_gemm<5><<<dim3(2,64), 256, 0, stream>>>(xb, WgfoT, gfo, 1024, 1024, 256,  gammac); // + gamma
  // level-2 bottleneck GEMM: ef = sigmoid(fmid @ Wf2)
  k_gemm<3><<<dim3(8,64), 256, 0, stream>>>(gfo + 16, Wf2T, efb, 64, 256, 1024, nullptr);

  // sequential recurrence (writes obuf = xb)
  k_scan<<<512, 64, 0, stream>>>(qb, kb, vb, efb, gammac, obuf);

  // og gate: sigmoid(ogmid @ Wog2) -> ogs (= qb, dead after scan)
  k_gemm<3><<<dim3(8,64), 256, 0, stream>>>(gfo + 80, Wog2T, ogs, 64, 256, 1024, nullptr);

  // gate + layernorm (writes onb = kb)
  k_gate_ln<<<8192, 256, 0, stream>>>(obuf, ogs, nw, onb);

  // final projection -> d_out (fp32)
  k_gemm<0><<<dim3(8,64), 256, 0, stream>>>(onb, WoT, (float*)d_out, 1024, 1024, 1024, nullptr);
}

// Round 6
// 742.786 us; speedup vs baseline: 1.3698x; 1.3698x over previous
//
#include <hip/hip_runtime.h>
#include <hip/hip_bf16.h>

#define B_  4
#define T_  2048
#define D_  1024
#define H_  16
#define HD_ 64
#define M_  (B_*T_)   // 8192
#define CH_ 16        // scan chunk (steps per LDS buffer)

typedef __attribute__((ext_vector_type(4))) float f32x4;
typedef __attribute__((ext_vector_type(8))) short bf16x8;

__device__ __forceinline__ float sigmoidf_(float x){ return 1.0f/(1.0f+__expf(-x)); }
__device__ __forceinline__ float siluf_(float x){ return x/(1.0f+__expf(-x)); }

// f32 -> bf16 (RNE), raw ushort
__device__ __forceinline__ unsigned short f2bf(float f){
  unsigned int u = __float_as_uint(f);
  unsigned int r = (u + 0x7FFFu + ((u >> 16) & 1u)) >> 16;
  return (unsigned short)r;
}
__device__ __forceinline__ float bf2f(unsigned short u){
  return __uint_as_float(((unsigned int)u) << 16);
}

// async global->LDS, 16 bytes per lane (dest = wave-uniform base + lane*16)
__device__ __forceinline__ void gload16(const void* g, void* l){
  using GP = const __attribute__((address_space(1))) unsigned int*;
  using LP = __attribute__((address_space(3))) unsigned int*;
  __builtin_amdgcn_global_load_lds(
      reinterpret_cast<GP>(reinterpret_cast<unsigned long long>(g)),
      reinterpret_cast<LP>(reinterpret_cast<unsigned long long>(l)),
      16, 0, 0);
}
// async global->LDS, 4 bytes per lane
__device__ __forceinline__ void gload4(const void* g, void* l){
  using GP = const __attribute__((address_space(1))) unsigned int*;
  using LP = __attribute__((address_space(3))) unsigned int*;
  __builtin_amdgcn_global_load_lds(
      reinterpret_cast<GP>(reinterpret_cast<unsigned long long>(g)),
      reinterpret_cast<LP>(reinterpret_cast<unsigned long long>(l)),
      4, 0, 0);
}

// DPP butterfly add stage (VALU, no DS pipe)
template<int CTRL>
__device__ __forceinline__ float dpp_add(float x){
  int y = __builtin_amdgcn_update_dpp(0, __float_as_int(x), CTRL, 0xF, 0xF, true);
  return x + __int_as_float(y);
}
// reduce over 16-lane rows (kseg = lane&15): xor1, xor2, then half/full mirror
// (mirrors are exact xor4/xor8 equivalents once 4-/8-groups are uniform)
__device__ __forceinline__ float row_reduce16(float x){
  x = dpp_add<0xB1>(x);    // quad_perm xor1
  x = dpp_add<0x4E>(x);    // quad_perm xor2
  x = dpp_add<0x141>(x);   // ROW_HALF_MIRROR (== xor4)
  x = dpp_add<0x140>(x);   // ROW_MIRROR      (== xor8)
  return x;
}

// unpack 4 bf16 (uint2) -> f32x4
__device__ __forceinline__ f32x4 unpack4(uint2 d){
  f32x4 r;
  r[0] = __uint_as_float(d.x << 16);
  r[1] = __uint_as_float(d.x & 0xffff0000u);
  r[2] = __uint_as_float(d.y << 16);
  r[3] = __uint_as_float(d.y & 0xffff0000u);
  return r;
}

// ---------------- converts ----------------
__global__ __launch_bounds__(256) void k_f32_to_bf16(const float* __restrict__ src,
                                                     unsigned short* __restrict__ dst, int n){
  int i = (blockIdx.x * 256 + threadIdx.x) * 4;
  if (i >= n) return;
  float4 v = *reinterpret_cast<const float4*>(src + i);
  ushort4 o;
  o.x = f2bf(v.x); o.y = f2bf(v.y); o.z = f2bf(v.z); o.w = f2bf(v.w);
  *reinterpret_cast<ushort4*>(dst + i) = o;
}

// dst[Nd][K] bf16 = transpose(src[K][Ns]); rows Ns..Nd zero-padded
__global__ void k_transpose_bf16(const float* __restrict__ src, unsigned short* __restrict__ dst,
                                 int K, int Ns, int Nd){
  __shared__ float tile[32][33];
  int k0 = blockIdx.x * 32, n0 = blockIdx.y * 32;
  int lx = threadIdx.x, ly = threadIdx.y;           // 32 x 8
  for (int i = ly; i < 32; i += 8){
    int n = n0 + lx;
    tile[i][lx] = (n < Ns) ? src[(size_t)(k0 + i) * Ns + n] : 0.0f;
  }
  __syncthreads();
  for (int i = ly; i < 32; i += 8){
    int n = n0 + i;
    if (n < Nd) dst[(size_t)n * K + k0 + lx] = f2bf(tile[lx][i]);
  }
}

// ---------------- bf16 MFMA GEMM: C[M,N] = A[M,K(lda)] * BT[N,K]^T ----------------
// 128x128 tile, BK=32, 4 waves (2x2), 16x16x32 MFMA, global_load_lds + XOR swizzle.
// EPI: 0 = f32 store, 1 = bf16, 2 = silu->bf16, 3 = sigmoid->bf16,
//      4 = silu + per-64col-head l2norm -> bf16, 5 = bf16 + gamma side-channel (cols<16)
template<int EPI>
__global__ __launch_bounds__(256) void k_gemm(const unsigned short* __restrict__ A,
                                              const unsigned short* __restrict__ BT,
                                              void* __restrict__ Cout,
                                              int K, int lda, int ldc,
                                              float* __restrict__ extra){
  __shared__ __align__(16) unsigned short As[128*32];
  __shared__ __align__(16) unsigned short Bs[128*32];
  const int tid = threadIdx.x;
  const int l = tid & 63, w = tid >> 6;
  const int wm = w >> 1, wn = w & 1;
  const int m0 = blockIdx.y * 128, n0 = blockIdx.x * 128;
  const int lr = l & 15, kg = l >> 4;

  f32x4 acc[4][4];
#pragma unroll
  for (int i = 0; i < 4; ++i)
#pragma unroll
    for (int j = 0; j < 4; ++j) acc[i][j] = 0.0f;

  for (int kt = 0; kt < K; kt += 32){
    __syncthreads();
    {
      int ch = tid;
      int row = ch >> 2;
      int sw  = (row & 3) ^ ((row >> 2) & 3);
      int cc  = (ch & 3) ^ sw;
      gload16(A  + (size_t)(m0 + row) * lda + kt + cc * 8, (char*)As + ch * 16);
      gload16(BT + (size_t)(n0 + row) * K   + kt + cc * 8, (char*)Bs + ch * 16);
      ch = tid + 256;
      row = ch >> 2;
      sw  = (row & 3) ^ ((row >> 2) & 3);
      cc  = (ch & 3) ^ sw;
      gload16(A  + (size_t)(m0 + row) * lda + kt + cc * 8, (char*)As + ch * 16);
      gload16(BT + (size_t)(n0 + row) * K   + kt + cc * 8, (char*)Bs + ch * 16);
    }
    __syncthreads();

    bf16x8 af[4], bfr[4];
#pragma unroll
    for (int mi = 0; mi < 4; ++mi){
      int row = wm*64 + mi*16 + lr;
      int sw  = (row & 3) ^ ((row >> 2) & 3);
      af[mi]  = *reinterpret_cast<const bf16x8*>((const char*)As + row*64 + ((kg ^ sw) * 16));
    }
#pragma unroll
    for (int ni = 0; ni < 4; ++ni){
      int col = wn*64 + ni*16 + lr;
      int sw  = (col & 3) ^ ((col >> 2) & 3);
      bfr[ni] = *reinterpret_cast<const bf16x8*>((const char*)Bs + col*64 + ((kg ^ sw) * 16));
    }
#pragma unroll
    for (int mi = 0; mi < 4; ++mi)
#pragma unroll
      for (int ni = 0; ni < 4; ++ni)
        acc[mi][ni] = __builtin_amdgcn_mfma_f32_16x16x32_bf16(af[mi], bfr[ni], acc[mi][ni], 0, 0, 0);
  }

#pragma unroll
  for (int mi = 0; mi < 4; ++mi){
    if (EPI == 4){
      // silu then l2-normalize each row over this wave's 64-col head block
#pragma unroll
      for (int r = 0; r < 4; ++r){
        float vals[4]; float ss = 0.0f;
#pragma unroll
        for (int ni = 0; ni < 4; ++ni){ vals[ni] = siluf_(acc[mi][ni][r]); ss += vals[ni]*vals[ni]; }
        ss += __shfl_xor(ss, 1); ss += __shfl_xor(ss, 2);
        ss += __shfl_xor(ss, 4); ss += __shfl_xor(ss, 8);
        const float inv = 1.0f / fmaxf(sqrtf(ss), 1e-12f);
        const int row = m0 + wm*64 + mi*16 + kg*4 + r;
#pragma unroll
        for (int ni = 0; ni < 4; ++ni){
          const int col = n0 + wn*64 + ni*16 + lr;
          ((unsigned short*)Cout)[(size_t)row*ldc + col] = f2bf(vals[ni]*inv);
        }
      }
    } else {
#pragma unroll
      for (int ni = 0; ni < 4; ++ni)
#pragma unroll
        for (int r = 0; r < 4; ++r){
          const int row = m0 + wm*64 + mi*16 + kg*4 + r;
          const int col = n0 + wn*64 + ni*16 + lr;
          const float v = acc[mi][ni][r];
          if (EPI == 0){
            ((float*)Cout)[(size_t)row*ldc + col] = v;
          } else {
            float ov = v;
            if (EPI == 2) ov = siluf_(v);
            if (EPI == 3) ov = sigmoidf_(v);
            ((unsigned short*)Cout)[(size_t)row*ldc + col] = f2bf(ov);
            if (EPI == 5 && col < 16)
              extra[((size_t)(row >> 11) * 16 + col) * 2048 + (row & 2047)] = -sigmoidf_(v);
          }
        }
    }
  }
}

// ---------------- sequential DPLR scan ----------------
// grid: 1024 blocks; bh = blk&63, vg = blk>>6 (16 v-groups of 4 columns).
// 64 threads (one wave). lane: kseg = l&15 (4 k-elems each), c = l>>4 (column).
// S[k][col]: 1x f32x4 per lane. All cross-lane reduction via DPP (VALU pipe);
// per-step LDS reads software-pipelined one step ahead; bf16 unpacked inline.
__global__ __launch_bounds__(64) void k_scan(const unsigned short* __restrict__ qs,
                                             const unsigned short* __restrict__ ks,
                                             const unsigned short* __restrict__ vb,
                                             const unsigned short* __restrict__ eb,
                                             const float* __restrict__ gammac,
                                             unsigned short* __restrict__ o){
  __shared__ __align__(16) unsigned short qS[2][CH_*64];
  __shared__ __align__(16) unsigned short kS[2][CH_*64];
  __shared__ __align__(16) unsigned short eS[2][CH_*64];
  __shared__ __align__(16) unsigned short vS[2][CH_*4];
  __shared__ __align__(16) float          gS[2][CH_];

  const int bh = blockIdx.x & 63, vg = blockIdx.x >> 6;
  const int l = threadIdx.x;
  const int kseg = l & 15, c = l >> 4;
  const int b = bh >> 4, h = bh & 15;
  const int bT = b * T_;
  const int hc = h * HD_;
  const float* gb = gammac + (size_t)bh * T_;

  f32x4 S = 0.0f;

  auto stage = [&](int nb, int chk){
    const int t0 = chk * CH_;
#pragma unroll
    for (int i = 0; i < 2; ++i){
      const size_t src = (size_t)(bT + t0 + i*8 + (l>>3)) * D_ + hc + (l&7)*8;
      gload16(qs + src, (char*)&qS[nb][0] + i*1024 + l*16);
      gload16(ks + src, (char*)&kS[nb][0] + i*1024 + l*16);
      gload16(eb + src, (char*)&eS[nb][0] + i*1024 + l*16);
    }
    if (l < 32)
      gload4(vb + (size_t)(bT + t0 + (l>>1)) * D_ + hc + vg*4 + (l&1)*2,
             (char*)&vS[nb][0] + l*4);
    if (l < 4)
      gload16(gb + t0 + l*4, (char*)&gS[nb][0] + l*16);
  };

  stage(0, 0);
  asm volatile("s_waitcnt vmcnt(0)" ::: "memory");
  __builtin_amdgcn_sched_barrier(0);

  unsigned short* ob = o + (size_t)bT * D_ + hc + vg*4 + c;

  for (int chk = 0; chk < T_/CH_; ++chk){
    const int cur = chk & 1;
    if (chk + 1 < T_/CH_) stage(cur ^ 1, chk + 1);

    // preload step 0 of current chunk
    const char* qB = (const char*)&qS[cur][0];
    const char* kB = (const char*)&kS[cur][0];
    const char* eB = (const char*)&eS[cur][0];
    uint2 dq = *(const uint2*)(qB + kseg*8);
    uint2 dk = *(const uint2*)(kB + kseg*8);
    uint2 de = *(const uint2*)(eB + kseg*8);
    unsigned short vraw = vS[cur][c];
    float graw = gS[cur][0];

#pragma unroll
    for (int s = 0; s < CH_; ++s){
      // issue next step's LDS loads (latency hidden under this step's math)
      uint2 nq = dq, nk = dk, ne = de; unsigned short nv = vraw; float ng = graw;
      if (s + 1 < CH_){
        nq = *(const uint2*)(qB + (s+1)*128 + kseg*8);
        nk = *(const uint2*)(kB + (s+1)*128 + kseg*8);
        ne = *(const uint2*)(eB + (s+1)*128 + kseg*8);
        nv = vS[cur][(s+1)*4 + c];
        ng = gS[cur][s+1];
      }

      f32x4 E = unpack4(de);
      f32x4 K = unpack4(dk);
      f32x4 Q = unpack4(dq);
      S *= E;                                   // decay
      f32x4 sv = (K * E) * S;                   // (k*ef) ⊙ S'
      float red = (sv[0]+sv[1]) + (sv[2]+sv[3]);
      red = row_reduce16(red);                  // sum over k (DPP butterfly)
      float tv = fmaf(graw, red, bf2f(vraw));   // gamma*sab + v
      S += K * tv;                              // S += k (sab+v)
      f32x4 ov = Q * S;
      float out = (ov[0]+ov[1]) + (ov[2]+ov[3]);
      out = row_reduce16(out);                  // sum over k (DPP butterfly)
      if (kseg == 0) ob[(size_t)(chk*CH_ + s) * D_] = f2bf(out);

      dq = nq; dk = nk; de = ne; vraw = nv; graw = ng;
    }
    asm volatile("s_waitcnt vmcnt(0)" ::: "memory");
    __builtin_amdgcn_sched_barrier(0);
  }
}

// ---------------- output gate (pre-sigmoided) + layernorm -> bf16 ----------------
__global__ __launch_bounds__(256) void k_gate_ln(const unsigned short* __restrict__ o,
                                                 const unsigned short* __restrict__ ogs,
                                                 const float* __restrict__ nw,
                                                 unsigned short* __restrict__ onb){
  const int tok = blockIdx.x;
  const int tid = threadIdx.x;
  const size_t base = (size_t)tok * D_ + tid * 4;
  ushort4 o4 = *(const ushort4*)(o + base);
  ushort4 g4 = *(const ushort4*)(ogs + base);
  float ov[4] = { bf2f(o4.x), bf2f(o4.y), bf2f(o4.z), bf2f(o4.w) };
  ov[0] *= bf2f(g4.x); ov[1] *= bf2f(g4.y);
  ov[2] *= bf2f(g4.z); ov[3] *= bf2f(g4.w);
  float s1 = ov[0] + ov[1] + ov[2] + ov[3];
  float s2 = ov[0]*ov[0] + ov[1]*ov[1] + ov[2]*ov[2] + ov[3]*ov[3];
#pragma unroll
  for (int off = 1; off < 64; off <<= 1){ s1 += __shfl_xor(s1, off); s2 += __shfl_xor(s2, off); }
  __shared__ float w1[4], w2[4];
  const int w = tid >> 6;
  if ((tid & 63) == 0){ w1[w] = s1; w2[w] = s2; }
  __syncthreads();
  s1 = w1[0] + w1[1] + w1[2] + w1[3];
  s2 = w2[0] + w2[1] + w2[2] + w2[3];
  const float mu  = s1 * (1.0f/1024.0f);
  const float var = s2 * (1.0f/1024.0f) - mu*mu;
  const float rs  = rsqrtf(var + 1e-5f);
  const float4 n4 = *(const float4*)(nw + tid * 4);
  ushort4 ou;
  ou.x = f2bf((ov[0] - mu) * rs * n4.x);
  ou.y = f2bf((ov[1] - mu) * rs * n4.y);
  ou.z = f2bf((ov[2] - mu) * rs * n4.z);
  ou.w = f2bf((ov[3] - mu) * rs * n4.w);
  *(ushort4*)(onb + base) = ou;
}

// ---------------- launcher ----------------
extern "C" void kernel_launch(void* const* d_in, const int* in_sizes, int n_in,
                              void* d_out, int out_size, void* d_ws, size_t ws_size,
                              hipStream_t stream){
  const float* x    = (const float*)d_in[0];
  const float* Wq   = (const float*)d_in[1];
  const float* Wk   = (const float*)d_in[2];
  const float* Wv   = (const float*)d_in[3];
  const float* Wg   = (const float*)d_in[4];
  const float* Wf1  = (const float*)d_in[5];
  const float* Wf2  = (const float*)d_in[6];
  const float* Wog1 = (const float*)d_in[7];
  const float* Wog2 = (const float*)d_in[8];
  const float* nw   = (const float*)d_in[9];
  const float* Wo   = (const float*)d_in[10];

  // workspace budget check (bail cleanly instead of faulting)
  if (ws_size < 97779712ull) return;

  char* base = (char*)d_ws;
  size_t off = 0;
  auto alloc = [&](size_t bytes)->char*{
    char* r = base + off; off += (bytes + 255) & ~(size_t)255; return r;
  };
  unsigned short* xb    = (unsigned short*)alloc((size_t)M_*D_*2);      // 16MB (scan out reuses)
  unsigned short* WqT   = (unsigned short*)alloc((size_t)D_*D_*2);      // 2MB
  unsigned short* WkT   = (unsigned short*)alloc((size_t)D_*D_*2);
  unsigned short* WvT   = (unsigned short*)alloc((size_t)D_*D_*2);
  unsigned short* WoT   = (unsigned short*)alloc((size_t)D_*D_*2);
  unsigned short* WgfoT = (unsigned short*)alloc((size_t)256*D_*2);     // 0.5MB
  unsigned short* Wf2T  = (unsigned short*)alloc((size_t)D_*64*2);      // 128KB
  unsigned short* Wog2T = (unsigned short*)alloc((size_t)D_*64*2);
  unsigned short* qb    = (unsigned short*)alloc((size_t)M_*D_*2);      // 16MB (og-sig reuses)
  unsigned short* kb    = (unsigned short*)alloc((size_t)M_*D_*2);      // 16MB (LN out reuses)
  unsigned short* vb    = (unsigned short*)alloc((size_t)M_*D_*2);      // 16MB
  unsigned short* gfo   = (unsigned short*)alloc((size_t)M_*256*2);     // 4MB
  unsigned short* efb   = (unsigned short*)alloc((size_t)M_*D_*2);      // 16MB
  float*          gammac= (float*)alloc((size_t)64*T_*4);               // 0.5MB
  // aliases (strictly ordered reuse):
  unsigned short* obuf = xb;   // xb dead after level-1 GEMMs; scan writes here
  unsigned short* ogs  = qb;   // qb dead after scan; og-sigmoid GEMM writes here
  unsigned short* onb  = kb;   // kb dead after scan; gate_ln writes here

  dim3 blkT(32, 8);

  // converts / transposes
  k_f32_to_bf16<<<8192, 256, 0, stream>>>(x, xb, M_*D_);
  k_transpose_bf16<<<dim3(32,32), blkT, 0, stream>>>(Wq,   WqT,  1024, 1024, 1024);
  k_transpose_bf16<<<dim3(32,32), blkT, 0, stream>>>(Wk,   WkT,  1024, 1024, 1024);
  k_transpose_bf16<<<dim3(32,32), blkT, 0, stream>>>(Wv,   WvT,  1024, 1024, 1024);
  k_transpose_bf16<<<dim3(32,32), blkT, 0, stream>>>(Wo,   WoT,  1024, 1024, 1024);
  // fused bottleneck weights: rows 0-15 Wg^T, 16-79 Wf1^T, 80-143 Wog1^T, 144-255 zero
  k_transpose_bf16<<<dim3(32,1),  blkT, 0, stream>>>(Wg,   WgfoT,            1024, 16,  16);
  k_transpose_bf16<<<dim3(32,2),  blkT, 0, stream>>>(Wf1,  WgfoT + 16*1024,  1024, 64,  64);
  k_transpose_bf16<<<dim3(32,6),  blkT, 0, stream>>>(Wog1, WgfoT + 80*1024,  1024, 64, 176);
  k_transpose_bf16<<<dim3(2,32),  blkT, 0, stream>>>(Wf2,  Wf2T,  64, 1024, 1024);
  k_transpose_bf16<<<dim3(2,32),  blkT, 0, stream>>>(Wog2, Wog2T, 64, 1024, 1024);

  // level-1 projections with fused activations
  k_gemm<2><<<dim3(8,64), 256, 0, stream>>>(xb, WqT,   qb,  1024, 1024, 1024, nullptr); // silu
  k_gemm<4><<<dim3(8,64), 256, 0, stream>>>(xb, WkT,   kb,  1024, 1024, 1024, nullptr); // silu+l2norm
  k_gemm<1><<<dim3(8,64), 256, 0, stream>>>(xb, WvT,   vb,  1024, 1024, 1024, nullptr); // plain
  k_gemm<5><<<dim3(2,64), 256, 0, stream>>>(xb, WgfoT, gfo, 1024, 1024, 256,  gammac); // + gamma
  // level-2 bottleneck GEMM: ef = sigmoid(fmid @ Wf2)
  k_gemm<3><<<dim3(8,64), 256, 0, stream>>>(gfo + 16, Wf2T, efb, 64, 256, 1024, nullptr);

  // sequential recurrence (writes obuf = xb)
  k_scan<<<1024, 64, 0, stream>>>(qb, kb, vb, efb, gammac, obuf);

  // og gate: sigmoid(ogmid @ Wog2) -> ogs (= qb, dead after scan)
  k_gemm<3><<<dim3(8,64), 256, 0, stream>>>(gfo + 80, Wog2T, ogs, 64, 256, 1024, nullptr);

  // gate + layernorm (writes onb = kb)
  k_gate_ln<<<8192, 256, 0, stream>>>(obuf, ogs, nw, onb);

  // final projection -> d_out (fp32)
  k_gemm<0><<<dim3(8,64), 256, 0, stream>>>(onb, WoT, (float*)d_out, 1024, 1024, 1024, nullptr);
}